// Round 1
// baseline (336.286 us; speedup 1.0000x reference)
//
#include <hip/hip_runtime.h>
#include <math.h>

#define BB 8
#define NN 576
#define DD 1024
#define KK 64
#define HH 512
#define WW 512
#define OUTD 256
#define HF 24
#define XSTRIDE 1032   // 1029 padded to 1032

// ---------------- K0: fmean[b,d] = mean_n feature_map[b,n,d] ----------------
__global__ __launch_bounds__(512) void k_fmean(const float* __restrict__ fm,
                                               float* __restrict__ fmean) {
    int g = blockIdx.x;            // 64 blocks: b = g/8, d-chunk = g%8 (128 d each)
    int b = g >> 3, dc = g & 7;
    int tid = threadIdx.x;         // 512 threads: 4 n-slices x 128 d
    int s = tid >> 7, dl = tid & 127;
    int d = dc * 128 + dl;
    const float* p = fm + (size_t)b * NN * DD + d;
    float acc = 0.f;
    for (int n = s; n < NN; n += 4) acc += p[(size_t)n * DD];
    __shared__ float red[4][128];
    red[s][dl] = acc;
    __syncthreads();
    if (s == 0) {
        float t = red[0][dl] + red[1][dl] + red[2][dl] + red[3][dl];
        fmean[b * DD + d] = t * (1.0f / 576.0f);
    }
}

// ---------------- K1: geometry (area, centroid, bbox) -> xbuf[...,1024..1028]
__global__ __launch_bounds__(1024) void k_geom(const int* __restrict__ masks,
                                               float* __restrict__ xbuf) {
    int bk = blockIdx.x;           // 512 blocks, one per (b,k)
    int tid = threadIdx.x;         // 1024
    const int4* mp = (const int4*)masks + (size_t)bk * 65536;  // 262144 ints / 4

    int cnt = 0, sx = 0, sy = 0;
    int xmn = 1 << 30, xmx = -1, ymn = 1 << 30, ymx = -1;

    for (int it = 0; it < 64; ++it) {
        int idx4 = tid + it * 1024;
        int4 m = mp[idx4];
        int p  = idx4 << 2;
        int y  = p >> 9;
        int xb = p & 511;
        int m0 = (m.x != 0), m1 = (m.y != 0), m2 = (m.z != 0), m3 = (m.w != 0);
        cnt += m0 + m1 + m2 + m3;
        sx  += m0 * xb + m1 * (xb + 1) + m2 * (xb + 2) + m3 * (xb + 3);
        int any4 = m0 | m1 | m2 | m3;
        sy  += (m0 + m1 + m2 + m3) * y;
        if (m0) { xmn = min(xmn, xb);     xmx = max(xmx, xb);     }
        if (m1) { xmn = min(xmn, xb + 1); xmx = max(xmx, xb + 1); }
        if (m2) { xmn = min(xmn, xb + 2); xmx = max(xmx, xb + 2); }
        if (m3) { xmn = min(xmn, xb + 3); xmx = max(xmx, xb + 3); }
        if (any4) { ymn = min(ymn, y); ymx = max(ymx, y); }
    }

    // wave reduce (64 lanes)
    for (int off = 32; off > 0; off >>= 1) {
        cnt += __shfl_down(cnt, off);
        sx  += __shfl_down(sx,  off);
        sy  += __shfl_down(sy,  off);
        xmn = min(xmn, __shfl_down(xmn, off));
        xmx = max(xmx, __shfl_down(xmx, off));
        ymn = min(ymn, __shfl_down(ymn, off));
        ymx = max(ymx, __shfl_down(ymx, off));
    }
    __shared__ int r0[16], r1[16], r2[16], r3[16], r4[16], r5[16], r6[16];
    int wv = tid >> 6;
    if ((tid & 63) == 0) {
        r0[wv] = cnt; r1[wv] = sx; r2[wv] = sy;
        r3[wv] = xmn; r4[wv] = xmx; r5[wv] = ymn; r6[wv] = ymx;
    }
    __syncthreads();
    if (tid == 0) {
        for (int i = 1; i < 16; ++i) {
            cnt += r0[i]; sx += r1[i]; sy += r2[i];
            xmn = min(xmn, r3[i]); xmx = max(xmx, r4[i]);
            ymn = min(ymn, r5[i]); ymx = max(ymx, r6[i]);
        }
        float* gp = xbuf + (size_t)bk * XSTRIDE + DD;
        if (cnt >= 1) {
            float area = (float)cnt;
            float safe = fmaxf(area, 1.0f);
            gp[0] = (float)sx / safe * (1.0f / 512.0f);
            gp[1] = (float)sy / safe * (1.0f / 512.0f);
            gp[2] = area * (1.0f / 262144.0f);
            gp[3] = (float)(xmx - xmn + 1) * (1.0f / 512.0f);
            gp[4] = (float)(ymx - ymn + 1) * (1.0f / 512.0f);
        } else {
            gp[0] = 0.f; gp[1] = 0.f; gp[2] = 0.f; gp[3] = 0.f; gp[4] = 0.f;
        }
        gp[5] = 0.f; gp[6] = 0.f; gp[7] = 0.f;   // pad cols 1029..1031
    }
}

// ---------------- K2: masked pooling -> xbuf[...,0..1023] -------------------
__global__ __launch_bounds__(256) void k_pool(const int* __restrict__ masks,
                                              const float* __restrict__ fm,
                                              const float* __restrict__ fmean,
                                              float* __restrict__ xbuf) {
    int g = blockIdx.x;                      // 512 blocks
    int bk = (g & 7) * 64 + (g >> 3);        // XCD-bijective swizzle (512 % 8 == 0)
    int b = bk >> 6;
    int tid = threadIdx.x;                   // 256

    __shared__ float ms[NN];
    __shared__ float cred[4];
    __shared__ float s_inv;

    float lc = 0.f;
    for (int n = tid; n < NN; n += 256) {
        int i = n / HF, j = n % HF;
        int ri = (i * HH) / HF;
        int ci = (j * WW) / HF;
        int mv = masks[(size_t)bk * HH * WW + (size_t)ri * WW + ci];
        float f = (mv != 0) ? 1.f : 0.f;
        ms[n] = f;
        lc += f;
    }
    for (int off = 32; off > 0; off >>= 1) lc += __shfl_down(lc, off);
    if ((tid & 63) == 0) cred[tid >> 6] = lc;
    __syncthreads();
    if (tid == 0) {
        float s = cred[0] + cred[1] + cred[2] + cred[3];
        s_inv = 1.0f / fmaxf(s, 1e-6f);
    }
    __syncthreads();

    float a0 = 0.f, a1 = 0.f, a2 = 0.f, a3 = 0.f;
    const float* fp = fm + (size_t)b * NN * DD + tid;
    for (int n = 0; n < NN; ++n) {
        if (ms[n] != 0.f) {                  // block-uniform branch
            const float* r = fp + (size_t)n * DD;
            a0 += r[0]; a1 += r[256]; a2 += r[512]; a3 += r[768];
        }
    }
    float inv = s_inv;
    float* xp = xbuf + (size_t)bk * XSTRIDE;
    const float* mn = fmean + b * DD + tid;
    xp[tid]       = a0 * inv - mn[0];
    xp[tid + 256] = a1 * inv - mn[256];
    xp[tid + 512] = a2 * inv - mn[512];
    xp[tid + 768] = a3 * inv - mn[768];
}

// ---------------- K3: MLP (x@w1 -> gelu -> LN -> @w2 + b2) ------------------
__global__ __launch_bounds__(256) void k_mlp(const float* __restrict__ xbuf,
                                             const float* __restrict__ w1,
                                             const float* __restrict__ b1,
                                             const float* __restrict__ ln_g,
                                             const float* __restrict__ ln_b,
                                             const float* __restrict__ w2,
                                             const float* __restrict__ b2,
                                             float* __restrict__ out) {
    int g = blockIdx.x;        // 64 blocks, 8 rows each
    int row0 = g * 8;
    int tid = threadIdx.x;     // 256

    __shared__ float xs[8][XSTRIDE];     // 33 KB
    for (int i = tid; i < 8 * XSTRIDE; i += 256) {
        xs[i / XSTRIDE][i % XSTRIDE] = xbuf[(size_t)row0 * XSTRIDE + i];
    }
    __syncthreads();

    float h[8];
    float b1v = b1[tid];
    #pragma unroll
    for (int r = 0; r < 8; ++r) h[r] = b1v;
    for (int j = 0; j < 1029; ++j) {
        float wv = w1[j * OUTD + tid];
        #pragma unroll
        for (int r = 0; r < 8; ++r) h[r] += xs[r][j] * wv;
    }
    #pragma unroll
    for (int r = 0; r < 8; ++r) {
        float v = h[r];
        h[r] = 0.5f * v * (1.0f + erff(v * 0.70710678118654752f));
    }

    // LayerNorm stats across 256 lanes per row
    __shared__ float s1[4][8], s2[4][8];
    int wv_ = tid >> 6, ln_ = tid & 63;
    #pragma unroll
    for (int r = 0; r < 8; ++r) {
        float a = h[r], q = h[r] * h[r];
        for (int off = 32; off > 0; off >>= 1) {
            a += __shfl_down(a, off);
            q += __shfl_down(q, off);
        }
        if (ln_ == 0) { s1[wv_][r] = a; s2[wv_][r] = q; }
    }
    __syncthreads();
    __shared__ float mu_[8], rs_[8];
    if (tid < 8) {
        float a = s1[0][tid] + s1[1][tid] + s1[2][tid] + s1[3][tid];
        float q = s2[0][tid] + s2[1][tid] + s2[2][tid] + s2[3][tid];
        float mu = a * (1.0f / 256.0f);
        float var = q * (1.0f / 256.0f) - mu * mu;
        mu_[tid] = mu;
        rs_[tid] = rsqrtf(var + 1e-5f);
    }
    __syncthreads();

    __shared__ float hs[8][OUTD];
    float gv = ln_g[tid], bv = ln_b[tid];
    #pragma unroll
    for (int r = 0; r < 8; ++r) hs[r][tid] = (h[r] - mu_[r]) * rs_[r] * gv + bv;
    __syncthreads();

    float o[8];
    float b2v = b2[tid];
    #pragma unroll
    for (int r = 0; r < 8; ++r) o[r] = b2v;
    for (int j = 0; j < OUTD; ++j) {
        float wv2 = w2[j * OUTD + tid];
        #pragma unroll
        for (int r = 0; r < 8; ++r) o[r] += hs[r][j] * wv2;
    }
    #pragma unroll
    for (int r = 0; r < 8; ++r) out[(size_t)(row0 + r) * OUTD + tid] = o[r];
}

extern "C" void kernel_launch(void* const* d_in, const int* in_sizes, int n_in,
                              void* d_out, int out_size, void* d_ws, size_t ws_size,
                              hipStream_t stream) {
    const float* fm    = (const float*)d_in[0];
    const int*   masks = (const int*)d_in[1];
    const float* w1    = (const float*)d_in[2];
    const float* b1    = (const float*)d_in[3];
    const float* ln_g  = (const float*)d_in[4];
    const float* ln_b  = (const float*)d_in[5];
    const float* w2    = (const float*)d_in[6];
    const float* b2    = (const float*)d_in[7];
    float* out = (float*)d_out;

    float* fmean = (float*)d_ws;                 // 8*1024 floats = 32 KB
    float* xbuf  = fmean + BB * DD;              // 512*1032 floats ≈ 2.11 MB

    k_fmean<<<64, 512, 0, stream>>>(fm, fmean);
    k_geom <<<512, 1024, 0, stream>>>(masks, xbuf);
    k_pool <<<512, 256, 0, stream>>>(masks, fm, fmean, xbuf);
    k_mlp  <<<64, 256, 0, stream>>>(xbuf, w1, b1, ln_g, ln_b, w2, b2, out);
}

// Round 2
// 180.627 us; speedup vs baseline: 1.8618x; 1.8618x over previous
//
#include <hip/hip_runtime.h>
#include <math.h>

#define BB 8
#define NN 576
#define DD 1024
#define KK 64
#define HH 512
#define WW 512
#define OUTD 256
#define HF 24
#define XSTRIDE 1032   // 1029 padded to 1032 (16B-aligned rows)

// ---------------- K1: geometry + m_small + inv_msum -------------------------
// One block per (b,k). Streams all 262144 mask ints (the HBM floor).
__global__ __launch_bounds__(1024) void k_geom(const int* __restrict__ masks,
                                               float* __restrict__ msbuf,
                                               float* __restrict__ invbuf,
                                               float* __restrict__ xbuf) {
    int bk = blockIdx.x;           // 512 blocks
    int tid = threadIdx.x;         // 1024
    const int4* mp = (const int4*)masks + (size_t)bk * 65536;

    __shared__ float ms[NN];
    if (tid < NN) ms[tid] = 0.f;
    __syncthreads();

    int cnt = 0, sx = 0, sy = 0;
    int xmn = 1 << 30, xmx = -1, ymn = 1 << 30, ymx = -1;

    for (int it = 0; it < 64; ++it) {
        int idx4 = tid + (it << 10);
        int4 m = mp[idx4];
        int p  = idx4 << 2;
        int y  = p >> 9;
        int xb = p & 511;
        int m0 = (m.x != 0), m1 = (m.y != 0), m2 = (m.z != 0), m3 = (m.w != 0);
        int ms4 = m0 + m1 + m2 + m3;
        cnt += ms4;
        sx  += ms4 * xb + m1 + 2 * m2 + 3 * m3;
        sy  += ms4 * y;
        if (m0) { xmn = min(xmn, xb);     xmx = max(xmx, xb);     }
        if (m1) { xmn = min(xmn, xb + 1); xmx = max(xmx, xb + 1); }
        if (m2) { xmn = min(xmn, xb + 2); xmx = max(xmx, xb + 2); }
        if (m3) { xmn = min(xmn, xb + 3); xmx = max(xmx, xb + 3); }
        if (ms4) { ymn = min(ymn, y); ymx = max(ymx, y); }
        // nearest-neighbor sample membership (wave-uniform row check: cheap)
        int iy = (y * HF + 511) >> 9;
        if ((iy * 512) / HF == y) {
            #pragma unroll
            for (int e = 0; e < 4; ++e) {
                int me = (e == 0) ? m0 : (e == 1) ? m1 : (e == 2) ? m2 : m3;
                if (me) {
                    int x = xb + e;
                    int jx = (x * HF + 511) >> 9;
                    if ((jx * 512) / HF == x) ms[iy * HF + jx] = 1.0f;
                }
            }
        }
    }

    // wave reduce (64 lanes)
    for (int off = 32; off > 0; off >>= 1) {
        cnt += __shfl_down(cnt, off);
        sx  += __shfl_down(sx,  off);
        sy  += __shfl_down(sy,  off);
        xmn = min(xmn, __shfl_down(xmn, off));
        xmx = max(xmx, __shfl_down(xmx, off));
        ymn = min(ymn, __shfl_down(ymn, off));
        ymx = max(ymx, __shfl_down(ymx, off));
    }
    __shared__ int r0[16], r1[16], r2[16], r3[16], r4[16], r5[16], r6[16];
    int wv = tid >> 6;
    if ((tid & 63) == 0) {
        r0[wv] = cnt; r1[wv] = sx; r2[wv] = sy;
        r3[wv] = xmn; r4[wv] = xmx; r5[wv] = ymn; r6[wv] = ymx;
    }
    __syncthreads();
    if (tid == 0) {
        for (int i = 1; i < 16; ++i) {
            cnt += r0[i]; sx += r1[i]; sy += r2[i];
            xmn = min(xmn, r3[i]); xmx = max(xmx, r4[i]);
            ymn = min(ymn, r5[i]); ymx = max(ymx, r6[i]);
        }
        float* gp = xbuf + (size_t)bk * XSTRIDE + DD;
        if (cnt >= 1) {
            float area = (float)cnt;
            gp[0] = (float)sx / area * (1.0f / 512.0f);
            gp[1] = (float)sy / area * (1.0f / 512.0f);
            gp[2] = area * (1.0f / 262144.0f);
            gp[3] = (float)(xmx - xmn + 1) * (1.0f / 512.0f);
            gp[4] = (float)(ymx - ymn + 1) * (1.0f / 512.0f);
        } else {
            gp[0] = 0.f; gp[1] = 0.f; gp[2] = 0.f; gp[3] = 0.f; gp[4] = 0.f;
        }
        gp[5] = 0.f; gp[6] = 0.f; gp[7] = 0.f;   // pad cols 1029..1031
    }

    // m_small sum -> inv_msum; write m_small row
    float v = (tid < NN) ? ms[tid] : 0.f;
    for (int off = 32; off > 0; off >>= 1) v += __shfl_down(v, off);
    __shared__ float rs_[16];
    if ((tid & 63) == 0) rs_[wv] = v;
    __syncthreads();
    if (tid == 0) {
        float s = 0.f;
        for (int i = 0; i < 16; ++i) s += rs_[i];
        invbuf[bk] = 1.0f / fmaxf(s, 1e-6f);
    }
    if (tid < NN) msbuf[(size_t)bk * NN + tid] = ms[tid];
}

// ---------------- K2: tiled masked pooling (+fmean fused) -------------------
// Block = (b, 32-wide d-tile). fm read exactly once. Thread: 4 k x 2 d.
__global__ __launch_bounds__(256) void k_pool(const float* __restrict__ fm,
                                              const float* __restrict__ msbuf,
                                              const float* __restrict__ invbuf,
                                              float* __restrict__ xbuf) {
    int blk = blockIdx.x;          // 256 blocks
    int b = blk >> 5, dt = blk & 31;
    int d0 = dt << 5;
    int tid = threadIdx.x;         // 256
    int kg = tid >> 4, dg = tid & 15;      // compute map: k = 4kg..4kg+3, d = dg, dg+16
    int srow = tid >> 5, scol = tid & 31;  // fm staging map
    int kk_s = tid >> 2, qq = tid & 3;     // msk staging map

    __shared__ float fmT[32 * 68];   // [col][n] transposed, stride 68
    __shared__ float mskS[64 * 68];  // [k][n], stride 68
    __shared__ float fred[8][32];
    __shared__ float fmean_s[32];

    float acc[4][2] = {{0.f,0.f},{0.f,0.f},{0.f,0.f},{0.f,0.f}};
    float facc = 0.f;

    const float* fmb = fm + (size_t)b * NN * DD + d0;
    const float* msb = msbuf + (size_t)b * KK * NN;

    for (int ci = 0; ci < 9; ++ci) {
        int n0 = ci * 64;
        #pragma unroll
        for (int i = 0; i < 8; ++i) {
            int n = srow + 8 * i;
            float fv = fmb[(size_t)(n0 + n) * DD + scol];
            facc += fv;
            fmT[scol * 68 + n] = fv;
        }
        #pragma unroll
        for (int i = 0; i < 4; ++i) {
            float4 mv = *(const float4*)&msb[(size_t)kk_s * NN + n0 + qq * 16 + 4 * i];
            *(float4*)&mskS[kk_s * 68 + qq * 16 + 4 * i] = mv;
        }
        __syncthreads();
        #pragma unroll 4
        for (int q = 0; q < 16; ++q) {
            float4 fa = *(const float4*)&fmT[dg * 68 + 4 * q];
            float4 fb = *(const float4*)&fmT[(dg + 16) * 68 + 4 * q];
            #pragma unroll
            for (int kk = 0; kk < 4; ++kk) {
                float4 mv = *(const float4*)&mskS[(kg * 4 + kk) * 68 + 4 * q];
                acc[kk][0] += mv.x * fa.x + mv.y * fa.y + mv.z * fa.z + mv.w * fa.w;
                acc[kk][1] += mv.x * fb.x + mv.y * fb.y + mv.z * fb.z + mv.w * fb.w;
            }
        }
        __syncthreads();
    }

    // fmean for this block's 32 cols
    fred[srow][scol] = facc;
    __syncthreads();
    if (tid < 32) {
        float s = 0.f;
        #pragma unroll
        for (int i = 0; i < 8; ++i) s += fred[i][tid];
        fmean_s[tid] = s * (1.0f / 576.0f);
    }
    __syncthreads();

    float fm_a = fmean_s[dg], fm_b = fmean_s[dg + 16];
    #pragma unroll
    for (int kk = 0; kk < 4; ++kk) {
        int k = kg * 4 + kk;
        float inv = invbuf[b * KK + k];
        float* xp = xbuf + (size_t)(b * KK + k) * XSTRIDE + d0;
        xp[dg]      = acc[kk][0] * inv - fm_a;
        xp[dg + 16] = acc[kk][1] * inv - fm_b;
    }
}

// ---------------- K3: MLP, 4 rows/block, j-split across waves ---------------
__global__ __launch_bounds__(256) void k_mlp(const float* __restrict__ xbuf,
                                             const float* __restrict__ w1,
                                             const float* __restrict__ b1,
                                             const float* __restrict__ ln_g,
                                             const float* __restrict__ ln_b,
                                             const float* __restrict__ w2,
                                             const float* __restrict__ b2,
                                             float* __restrict__ out) {
    int row0 = blockIdx.x * 4;     // 128 blocks
    int tid = threadIdx.x;         // 256
    int w = tid >> 6, lane = tid & 63;
    int c4 = lane * 4;

    __shared__ float xs[4][XSTRIDE];      // 16.5 KB
    __shared__ float hp[4][4][OUTD];      // 16 KB partials [wave][row][col]
    __shared__ float hs[4][OUTD];         // 4 KB

    #pragma unroll
    for (int r = 0; r < 4; ++r)
        for (int c = tid; c < XSTRIDE; c += 256)
            xs[r][c] = xbuf[(size_t)(row0 + r) * XSTRIDE + c];
    __syncthreads();

    // ---- phase A: h = x @ w1, j-range per wave ----
    float acc[4][4] = {};
    int js = w * 260;
    int je = (w == 3) ? 1029 : js + 260;
    int j = js;
    for (; j + 4 <= je; j += 4) {
        float4 xv0 = *(const float4*)&xs[0][j];
        float4 xv1 = *(const float4*)&xs[1][j];
        float4 xv2 = *(const float4*)&xs[2][j];
        float4 xv3 = *(const float4*)&xs[3][j];
#define STEPA(jj, X0, X1, X2, X3)                                              \
        {                                                                      \
            float4 wv = *(const float4*)&w1[(size_t)(j + jj) * OUTD + c4];     \
            acc[0][0] += X0 * wv.x; acc[0][1] += X0 * wv.y;                    \
            acc[0][2] += X0 * wv.z; acc[0][3] += X0 * wv.w;                    \
            acc[1][0] += X1 * wv.x; acc[1][1] += X1 * wv.y;                    \
            acc[1][2] += X1 * wv.z; acc[1][3] += X1 * wv.w;                    \
            acc[2][0] += X2 * wv.x; acc[2][1] += X2 * wv.y;                    \
            acc[2][2] += X2 * wv.z; acc[2][3] += X2 * wv.w;                    \
            acc[3][0] += X3 * wv.x; acc[3][1] += X3 * wv.y;                    \
            acc[3][2] += X3 * wv.z; acc[3][3] += X3 * wv.w;                    \
        }
        STEPA(0, xv0.x, xv1.x, xv2.x, xv3.x)
        STEPA(1, xv0.y, xv1.y, xv2.y, xv3.y)
        STEPA(2, xv0.z, xv1.z, xv2.z, xv3.z)
        STEPA(3, xv0.w, xv1.w, xv2.w, xv3.w)
    }
    for (; j < je; ++j) {   // tail (wave 3 only: j = 1028)
        float xv[4] = {xs[0][j], xs[1][j], xs[2][j], xs[3][j]};
        #pragma unroll
        for (int ci = 0; ci < 4; ++ci) {
            float wvv = w1[(size_t)j * OUTD + c4 + ci];
            #pragma unroll
            for (int r = 0; r < 4; ++r) acc[r][ci] += xv[r] * wvv;
        }
    }
    #pragma unroll
    for (int r = 0; r < 4; ++r)
        *(float4*)&hp[w][r][c4] = make_float4(acc[r][0], acc[r][1], acc[r][2], acc[r][3]);
    __syncthreads();

    // ---- reduce partials, GELU, LayerNorm (thread = col) ----
    float h[4];
    float b1v = b1[tid];
    #pragma unroll
    for (int r = 0; r < 4; ++r)
        h[r] = b1v + hp[0][r][tid] + hp[1][r][tid] + hp[2][r][tid] + hp[3][r][tid];
    #pragma unroll
    for (int r = 0; r < 4; ++r) {
        float v = h[r];
        h[r] = 0.5f * v * (1.0f + erff(v * 0.70710678118654752f));
    }
    __shared__ float s1[4][4], s2[4][4];
    #pragma unroll
    for (int r = 0; r < 4; ++r) {
        float a = h[r], q = h[r] * h[r];
        for (int off = 32; off > 0; off >>= 1) {
            a += __shfl_down(a, off);
            q += __shfl_down(q, off);
        }
        if (lane == 0) { s1[w][r] = a; s2[w][r] = q; }
    }
    __syncthreads();
    __shared__ float mu_[4], rsd_[4];
    if (tid < 4) {
        float a = s1[0][tid] + s1[1][tid] + s1[2][tid] + s1[3][tid];
        float q = s2[0][tid] + s2[1][tid] + s2[2][tid] + s2[3][tid];
        float mu = a * (1.0f / 256.0f);
        float var = q * (1.0f / 256.0f) - mu * mu;
        mu_[tid] = mu;
        rsd_[tid] = rsqrtf(var + 1e-5f);
    }
    __syncthreads();
    float gv = ln_g[tid], bv = ln_b[tid];
    #pragma unroll
    for (int r = 0; r < 4; ++r)
        hs[r][tid] = (h[r] - mu_[r]) * rsd_[r] * gv + bv;
    __syncthreads();

    // ---- phase B: out = hs @ w2, j-range per wave (64 each) ----
    float a2[4][4] = {};
    int j2 = w * 64;
    for (int g = 0; g < 16; ++g, j2 += 4) {
        float4 h0 = *(const float4*)&hs[0][j2];
        float4 h1 = *(const float4*)&hs[1][j2];
        float4 h2 = *(const float4*)&hs[2][j2];
        float4 h3 = *(const float4*)&hs[3][j2];
#define STEPB(jj, X0, X1, X2, X3)                                              \
        {                                                                      \
            float4 wv = *(const float4*)&w2[(size_t)(j2 + jj) * OUTD + c4];    \
            a2[0][0] += X0 * wv.x; a2[0][1] += X0 * wv.y;                      \
            a2[0][2] += X0 * wv.z; a2[0][3] += X0 * wv.w;                      \
            a2[1][0] += X1 * wv.x; a2[1][1] += X1 * wv.y;                      \
            a2[1][2] += X1 * wv.z; a2[1][3] += X1 * wv.w;                      \
            a2[2][0] += X2 * wv.x; a2[2][1] += X2 * wv.y;                      \
            a2[2][2] += X2 * wv.z; a2[2][3] += X2 * wv.w;                      \
            a2[3][0] += X3 * wv.x; a2[3][1] += X3 * wv.y;                      \
            a2[3][2] += X3 * wv.z; a2[3][3] += X3 * wv.w;                      \
        }
        STEPB(0, h0.x, h1.x, h2.x, h3.x)
        STEPB(1, h0.y, h1.y, h2.y, h3.y)
        STEPB(2, h0.z, h1.z, h2.z, h3.z)
        STEPB(3, h0.w, h1.w, h2.w, h3.w)
    }
    #pragma unroll
    for (int r = 0; r < 4; ++r)
        *(float4*)&hp[w][r][c4] = make_float4(a2[r][0], a2[r][1], a2[r][2], a2[r][3]);
    __syncthreads();

    float b2v = b2[tid];
    #pragma unroll
    for (int r = 0; r < 4; ++r) {
        float o = b2v + hp[0][r][tid] + hp[1][r][tid] + hp[2][r][tid] + hp[3][r][tid];
        out[(size_t)(row0 + r) * OUTD + tid] = o;
    }
}

extern "C" void kernel_launch(void* const* d_in, const int* in_sizes, int n_in,
                              void* d_out, int out_size, void* d_ws, size_t ws_size,
                              hipStream_t stream) {
    const float* fm    = (const float*)d_in[0];
    const int*   masks = (const int*)d_in[1];
    const float* w1    = (const float*)d_in[2];
    const float* b1    = (const float*)d_in[3];
    const float* ln_g  = (const float*)d_in[4];
    const float* ln_b  = (const float*)d_in[5];
    const float* w2    = (const float*)d_in[6];
    const float* b2    = (const float*)d_in[7];
    float* out = (float*)d_out;

    float* msbuf  = (float*)d_ws;                    // 512*576 floats
    float* invbuf = msbuf + 512 * NN;                // 512 floats
    float* xbuf   = invbuf + 512;                    // 512*1032 floats

    k_geom<<<512, 1024, 0, stream>>>(masks, msbuf, invbuf, xbuf);
    k_pool<<<256, 256, 0, stream>>>(fm, msbuf, invbuf, xbuf);
    k_mlp <<<128, 256, 0, stream>>>(xbuf, w1, b1, ln_g, ln_b, w2, b2, out);
}

// Round 3
// 151.537 us; speedup vs baseline: 2.2192x; 1.1920x over previous
//
#include <hip/hip_runtime.h>
#include <math.h>

#define BB 8
#define NN 576
#define DD 1024
#define KK 64
#define HH 512
#define WW 512
#define OUTD 256
#define HF 24
#define XSTRIDE 1032   // 1029 padded to 1032 (16B-aligned rows)

// ---------------- K1: geometry + m_small + inv_msum -------------------------
// One block per (b,k). Streams all 262144 mask ints (the HBM floor).
// VALU diet: xb loop-invariant, y affine in it, bbox via colany/ctz + monotone
// y-range cndmask; m_small via 576 direct gathers issued before the stream.
__global__ __launch_bounds__(1024) void k_geom(const int* __restrict__ masks,
                                               float* __restrict__ msbuf,
                                               float* __restrict__ invbuf,
                                               float* __restrict__ xbuf) {
    int bk = blockIdx.x;           // 512 blocks
    int tid = threadIdx.x;         // 1024
    const int* mb = masks + (size_t)bk * (HH * WW);
    const int4* mp = (const int4*)mb;

    // early sampled gather for m_small (latency hides under the main stream)
    float msv = 0.f;
    if (tid < NN) {
        int i = tid / HF, j = tid - i * HF;
        int ri = (i * HH) / HF, ci = (j * WW) / HF;
        msv = (mb[ri * WW + ci] != 0) ? 1.f : 0.f;
    }

    const int y0 = tid >> 7;             // row offset within 8-row stripe
    const int xb = (tid & 127) << 2;     // loop-invariant column base
    int cnt = 0, w3a = 0, syr = 0, colany = 0;
    int ymn_it = 1 << 20, ymx_it = -1;

    #pragma unroll 8
    for (int it = 0; it < 64; ++it) {
        int4 m = mp[tid + (it << 10)];
        int m0 = min((unsigned)m.x, 1u);
        int m1 = min((unsigned)m.y, 1u);
        int m2 = min((unsigned)m.z, 1u);
        int m3 = min((unsigned)m.w, 1u);
        int sum4 = m0 + m1 + m2 + m3;
        int mask4 = m0 | (m1 << 1) | (m2 << 2) | (m3 << 3);
        cnt += sum4;
        w3a += m1 + (m2 << 1) + ((m3 << 1) + m3);
        syr += sum4 * it;
        colany |= mask4;
        if (mask4) { ymn_it = min(ymn_it, it); ymx_it = it; }  // y monotone in it
    }

    // per-lane finalize
    int sx = xb * cnt + w3a;
    int sy = (syr << 3) + y0 * cnt;
    int xmn = colany ? xb + __builtin_ctz((unsigned)colany) : (1 << 30);
    int xmx = colany ? xb + (31 - __builtin_clz((unsigned)colany)) : -1;
    int ymn = (ymx_it >= 0) ? (ymn_it << 3) + y0 : (1 << 30);
    int ymx = (ymx_it >= 0) ? (ymx_it << 3) + y0 : -1;

    // wave reduce (64 lanes)
    for (int off = 32; off > 0; off >>= 1) {
        cnt += __shfl_down(cnt, off);
        sx  += __shfl_down(sx,  off);
        sy  += __shfl_down(sy,  off);
        xmn = min(xmn, __shfl_down(xmn, off));
        xmx = max(xmx, __shfl_down(xmx, off));
        ymn = min(ymn, __shfl_down(ymn, off));
        ymx = max(ymx, __shfl_down(ymx, off));
    }
    __shared__ int r0[16], r1[16], r2[16], r3[16], r4[16], r5[16], r6[16];
    int wv = tid >> 6;
    if ((tid & 63) == 0) {
        r0[wv] = cnt; r1[wv] = sx; r2[wv] = sy;
        r3[wv] = xmn; r4[wv] = xmx; r5[wv] = ymn; r6[wv] = ymx;
    }
    __syncthreads();
    if (tid == 0) {
        for (int i = 1; i < 16; ++i) {
            cnt += r0[i]; sx += r1[i]; sy += r2[i];
            xmn = min(xmn, r3[i]); xmx = max(xmx, r4[i]);
            ymn = min(ymn, r5[i]); ymx = max(ymx, r6[i]);
        }
        float* gp = xbuf + (size_t)bk * XSTRIDE + DD;
        if (cnt >= 1) {
            float area = (float)cnt;
            gp[0] = (float)sx / area * (1.0f / 512.0f);
            gp[1] = (float)sy / area * (1.0f / 512.0f);
            gp[2] = area * (1.0f / 262144.0f);
            gp[3] = (float)(xmx - xmn + 1) * (1.0f / 512.0f);
            gp[4] = (float)(ymx - ymn + 1) * (1.0f / 512.0f);
        } else {
            gp[0] = 0.f; gp[1] = 0.f; gp[2] = 0.f; gp[3] = 0.f; gp[4] = 0.f;
        }
        gp[5] = 0.f; gp[6] = 0.f; gp[7] = 0.f;   // pad cols 1029..1031
    }

    // m_small sum -> inv_msum; write m_small row
    float v = msv;
    for (int off = 32; off > 0; off >>= 1) v += __shfl_down(v, off);
    __shared__ float rs_[16];
    if ((tid & 63) == 0) rs_[wv] = v;
    __syncthreads();
    if (tid == 0) {
        float s = 0.f;
        for (int i = 0; i < 16; ++i) s += rs_[i];
        invbuf[bk] = 1.0f / fmaxf(s, 1e-6f);
    }
    if (tid < NN) msbuf[(size_t)bk * NN + tid] = msv;
}

// ---------------- K2: tiled masked pooling (+fmean fused) -------------------
// 256 blocks (b, 32-d tile) x 512 threads = 8 waves/CU. Two n-teams:
// team 0 -> chunks 0..4, team 1 -> chunks 5..8, private LDS buffers,
// partials combined at the end. fm read from HBM exactly once.
__global__ __launch_bounds__(512) void k_pool(const float* __restrict__ fm,
                                              const float* __restrict__ msbuf,
                                              const float* __restrict__ invbuf,
                                              float* __restrict__ xbuf) {
    int blk = blockIdx.x;          // 256 blocks
    int b = blk >> 5, dt = blk & 31;
    int d0 = dt << 5;
    int tid = threadIdx.x;         // 512
    int team = tid >> 8, ttid = tid & 255;
    int kg = ttid >> 4, dg = ttid & 15;    // compute: k = 4kg..4kg+3, d = dg, dg+16
    int frow = tid >> 3, fc4 = (tid & 7) << 2;   // fm staging: one float4/thr/buf
    int mk = tid >> 3, mf = tid & 7;             // msk staging: two float4/thr/buf

    __shared__ float fmT[2][32][68];   // [buf][col][n]
    __shared__ float mskS[2][64][68];  // [buf][k][n]
    __shared__ float fredL[64][32];
    __shared__ float pacc[256][12];    // padded for bank spread
    __shared__ float fmean_s[32];

    float acc[4][2] = {{0.f,0.f},{0.f,0.f},{0.f,0.f},{0.f,0.f}};
    float facc4[4] = {0.f, 0.f, 0.f, 0.f};

    const float* fmb = fm + (size_t)b * NN * DD + d0;
    const float* msb = msbuf + (size_t)b * KK * NN;

    for (int r = 0; r < 5; ++r) {
        {   // stage buf0 = chunk r
            int n0 = r << 6;
            float4 v = *(const float4*)&fmb[(size_t)(n0 + frow) * DD + fc4];
            facc4[0] += v.x; facc4[1] += v.y; facc4[2] += v.z; facc4[3] += v.w;
            fmT[0][fc4 + 0][frow] = v.x;
            fmT[0][fc4 + 1][frow] = v.y;
            fmT[0][fc4 + 2][frow] = v.z;
            fmT[0][fc4 + 3][frow] = v.w;
            float4 a = *(const float4*)&msb[(size_t)mk * NN + n0 + (mf << 2)];
            float4 c = *(const float4*)&msb[(size_t)mk * NN + n0 + ((mf + 8) << 2)];
            *(float4*)&mskS[0][mk][(mf << 2)] = a;
            *(float4*)&mskS[0][mk][((mf + 8) << 2)] = c;
        }
        if (r < 4) {  // stage buf1 = chunk 5+r
            int n0 = (5 + r) << 6;
            float4 v = *(const float4*)&fmb[(size_t)(n0 + frow) * DD + fc4];
            facc4[0] += v.x; facc4[1] += v.y; facc4[2] += v.z; facc4[3] += v.w;
            fmT[1][fc4 + 0][frow] = v.x;
            fmT[1][fc4 + 1][frow] = v.y;
            fmT[1][fc4 + 2][frow] = v.z;
            fmT[1][fc4 + 3][frow] = v.w;
            float4 a = *(const float4*)&msb[(size_t)mk * NN + n0 + (mf << 2)];
            float4 c = *(const float4*)&msb[(size_t)mk * NN + n0 + ((mf + 8) << 2)];
            *(float4*)&mskS[1][mk][(mf << 2)] = a;
            *(float4*)&mskS[1][mk][((mf + 8) << 2)] = c;
        }
        __syncthreads();
        int c = (team == 0) ? r : 5 + r;
        if (c < 9) {
            #pragma unroll 4
            for (int q = 0; q < 16; ++q) {
                float4 fa = *(const float4*)&fmT[team][dg][q << 2];
                float4 fb = *(const float4*)&fmT[team][dg + 16][q << 2];
                #pragma unroll
                for (int kk = 0; kk < 4; ++kk) {
                    float4 mv = *(const float4*)&mskS[team][(kg << 2) + kk][q << 2];
                    acc[kk][0] += mv.x * fa.x + mv.y * fa.y + mv.z * fa.z + mv.w * fa.w;
                    acc[kk][1] += mv.x * fb.x + mv.y * fb.y + mv.z * fb.z + mv.w * fb.w;
                }
            }
        }
        __syncthreads();
    }

    // publish partials
    fredL[frow][fc4 + 0] = facc4[0];
    fredL[frow][fc4 + 1] = facc4[1];
    fredL[frow][fc4 + 2] = facc4[2];
    fredL[frow][fc4 + 3] = facc4[3];
    if (team == 1) {
        #pragma unroll
        for (int kk = 0; kk < 4; ++kk) {
            pacc[ttid][kk * 2 + 0] = acc[kk][0];
            pacc[ttid][kk * 2 + 1] = acc[kk][1];
        }
    }
    __syncthreads();
    if (tid < 32) {
        float s = 0.f;
        #pragma unroll
        for (int i = 0; i < 64; ++i) s += fredL[i][tid];
        fmean_s[tid] = s * (1.0f / 576.0f);
    }
    __syncthreads();
    if (team == 0) {
        float fm_a = fmean_s[dg], fm_b = fmean_s[dg + 16];
        #pragma unroll
        for (int kk = 0; kk < 4; ++kk) {
            int k = kg * 4 + kk;
            float inv = invbuf[b * KK + k];
            float* xp = xbuf + (size_t)(b * KK + k) * XSTRIDE + d0;
            xp[dg]      = (acc[kk][0] + pacc[ttid][kk * 2 + 0]) * inv - fm_a;
            xp[dg + 16] = (acc[kk][1] + pacc[ttid][kk * 2 + 1]) * inv - fm_b;
        }
    }
}

// ---------------- K3: MLP, 4 rows/block, 512 thr, 8-way j-split -------------
__global__ __launch_bounds__(512) void k_mlp(const float* __restrict__ xbuf,
                                             const float* __restrict__ w1,
                                             const float* __restrict__ b1,
                                             const float* __restrict__ ln_g,
                                             const float* __restrict__ ln_b,
                                             const float* __restrict__ w2,
                                             const float* __restrict__ b2,
                                             float* __restrict__ out) {
    int row0 = blockIdx.x * 4;     // 128 blocks
    int tid = threadIdx.x;         // 512
    int w = tid >> 6, lane = tid & 63;
    int c4 = lane * 4;
    int col = tid & 255, rhalf = tid >> 8;

    __shared__ float xs[4][XSTRIDE];      // 16.5 KB
    __shared__ float hp[8][4][OUTD];      // 32 KB partials [wave][row][col]
    __shared__ float hs[4][OUTD];         // 4 KB

    #pragma unroll
    for (int r = 0; r < 4; ++r)
        for (int c = tid; c < XSTRIDE; c += 512)
            xs[r][c] = xbuf[(size_t)(row0 + r) * XSTRIDE + c];
    __syncthreads();

    // ---- phase A: h = x @ w1, j-range per wave ----
    float acc[4][4] = {};
    int js = w * 129;
    int je = min(1029, js + 129);
    int j = js;
    for (; j + 4 <= je; j += 4) {
        float4 xv0 = *(const float4*)&xs[0][j];
        float4 xv1 = *(const float4*)&xs[1][j];
        float4 xv2 = *(const float4*)&xs[2][j];
        float4 xv3 = *(const float4*)&xs[3][j];
#define STEPA(jj, X0, X1, X2, X3)                                              \
        {                                                                      \
            float4 wv = *(const float4*)&w1[(size_t)(j + jj) * OUTD + c4];     \
            acc[0][0] += X0 * wv.x; acc[0][1] += X0 * wv.y;                    \
            acc[0][2] += X0 * wv.z; acc[0][3] += X0 * wv.w;                    \
            acc[1][0] += X1 * wv.x; acc[1][1] += X1 * wv.y;                    \
            acc[1][2] += X1 * wv.z; acc[1][3] += X1 * wv.w;                    \
            acc[2][0] += X2 * wv.x; acc[2][1] += X2 * wv.y;                    \
            acc[2][2] += X2 * wv.z; acc[2][3] += X2 * wv.w;                    \
            acc[3][0] += X3 * wv.x; acc[3][1] += X3 * wv.y;                    \
            acc[3][2] += X3 * wv.z; acc[3][3] += X3 * wv.w;                    \
        }
        STEPA(0, xv0.x, xv1.x, xv2.x, xv3.x)
        STEPA(1, xv0.y, xv1.y, xv2.y, xv3.y)
        STEPA(2, xv0.z, xv1.z, xv2.z, xv3.z)
        STEPA(3, xv0.w, xv1.w, xv2.w, xv3.w)
    }
    for (; j < je; ++j) {   // tail
        float xv[4] = {xs[0][j], xs[1][j], xs[2][j], xs[3][j]};
        #pragma unroll
        for (int ci = 0; ci < 4; ++ci) {
            float wvv = w1[(size_t)j * OUTD + c4 + ci];
            #pragma unroll
            for (int r = 0; r < 4; ++r) acc[r][ci] += xv[r] * wvv;
        }
    }
    #pragma unroll
    for (int r = 0; r < 4; ++r)
        *(float4*)&hp[w][r][c4] = make_float4(acc[r][0], acc[r][1], acc[r][2], acc[r][3]);
    __syncthreads();

    // ---- reduce partials, GELU, LayerNorm (thread = (rhalf, col)) ----
    float h2[2];
    float b1v = b1[col];
    #pragma unroll
    for (int r2 = 0; r2 < 2; ++r2) {
        int r = rhalf * 2 + r2;
        float s = b1v;
        #pragma unroll
        for (int ww = 0; ww < 8; ++ww) s += hp[ww][r][col];
        h2[r2] = 0.5f * s * (1.0f + erff(s * 0.70710678118654752f));
    }
    __shared__ float s1[8][2], s2[8][2];
    #pragma unroll
    for (int r2 = 0; r2 < 2; ++r2) {
        float a = h2[r2], q = h2[r2] * h2[r2];
        for (int off = 32; off > 0; off >>= 1) {
            a += __shfl_down(a, off);
            q += __shfl_down(q, off);
        }
        if (lane == 0) { s1[w][r2] = a; s2[w][r2] = q; }
    }
    __syncthreads();
    __shared__ float mu_[4], rsd_[4];
    if (tid < 4) {
        int rh = tid >> 1, r2 = tid & 1;
        float a = 0.f, q = 0.f;
        #pragma unroll
        for (int i = 0; i < 4; ++i) {
            a += s1[rh * 4 + i][r2];
            q += s2[rh * 4 + i][r2];
        }
        float mu = a * (1.0f / 256.0f);
        float var = q * (1.0f / 256.0f) - mu * mu;
        mu_[tid] = mu;
        rsd_[tid] = rsqrtf(var + 1e-5f);
    }
    __syncthreads();
    float gv = ln_g[col], bv = ln_b[col];
    #pragma unroll
    for (int r2 = 0; r2 < 2; ++r2) {
        int r = rhalf * 2 + r2;
        hs[r][col] = (h2[r2] - mu_[r]) * rsd_[r] * gv + bv;
    }
    __syncthreads();

    // ---- phase B: out = hs @ w2, j-range per wave (32 each) ----
    float a2[4][4] = {};
    int j2 = w * 32;
    for (int g = 0; g < 8; ++g, j2 += 4) {
        float4 h0 = *(const float4*)&hs[0][j2];
        float4 h1 = *(const float4*)&hs[1][j2];
        float4 h2v = *(const float4*)&hs[2][j2];
        float4 h3 = *(const float4*)&hs[3][j2];
#define STEPB(jj, X0, X1, X2, X3)                                              \
        {                                                                      \
            float4 wv = *(const float4*)&w2[(size_t)(j2 + jj) * OUTD + c4];    \
            a2[0][0] += X0 * wv.x; a2[0][1] += X0 * wv.y;                      \
            a2[0][2] += X0 * wv.z; a2[0][3] += X0 * wv.w;                      \
            a2[1][0] += X1 * wv.x; a2[1][1] += X1 * wv.y;                      \
            a2[1][2] += X1 * wv.z; a2[1][3] += X1 * wv.w;                      \
            a2[2][0] += X2 * wv.x; a2[2][1] += X2 * wv.y;                      \
            a2[2][2] += X2 * wv.z; a2[2][3] += X2 * wv.w;                      \
            a2[3][0] += X3 * wv.x; a2[3][1] += X3 * wv.y;                      \
            a2[3][2] += X3 * wv.z; a2[3][3] += X3 * wv.w;                      \
        }
        STEPB(0, h0.x, h1.x, h2v.x, h3.x)
        STEPB(1, h0.y, h1.y, h2v.y, h3.y)
        STEPB(2, h0.z, h1.z, h2v.z, h3.z)
        STEPB(3, h0.w, h1.w, h2v.w, h3.w)
    }
    #pragma unroll
    for (int r = 0; r < 4; ++r)
        *(float4*)&hp[w][r][c4] = make_float4(a2[r][0], a2[r][1], a2[r][2], a2[r][3]);
    __syncthreads();

    float b2v = b2[col];
    #pragma unroll
    for (int r2 = 0; r2 < 2; ++r2) {
        int r = rhalf * 2 + r2;
        float o = b2v;
        #pragma unroll
        for (int ww = 0; ww < 8; ++ww) o += hp[ww][r][col];
        out[(size_t)(row0 + r) * OUTD + col] = o;
    }
}

extern "C" void kernel_launch(void* const* d_in, const int* in_sizes, int n_in,
                              void* d_out, int out_size, void* d_ws, size_t ws_size,
                              hipStream_t stream) {
    const float* fm    = (const float*)d_in[0];
    const int*   masks = (const int*)d_in[1];
    const float* w1    = (const float*)d_in[2];
    const float* b1    = (const float*)d_in[3];
    const float* ln_g  = (const float*)d_in[4];
    const float* ln_b  = (const float*)d_in[5];
    const float* w2    = (const float*)d_in[6];
    const float* b2    = (const float*)d_in[7];
    float* out = (float*)d_out;

    float* msbuf  = (float*)d_ws;                    // 512*576 floats
    float* invbuf = msbuf + 512 * NN;                // 512 floats
    float* xbuf   = invbuf + 512;                    // 512*1032 floats

    k_geom<<<512, 1024, 0, stream>>>(masks, msbuf, invbuf, xbuf);
    k_pool<<<256, 512, 0, stream>>>(fm, msbuf, invbuf, xbuf);
    k_mlp <<<128, 512, 0, stream>>>(xbuf, w1, b1, ln_g, ln_b, w2, b2, out);
}

// Round 5
// 131.116 us; speedup vs baseline: 2.5648x; 1.1558x over previous
//
#include <hip/hip_runtime.h>
#include <math.h>

#define BB 8
#define NN 576
#define DD 1024
#define KK 64
#define HH 512
#define WW 512
#define OUTD 256
#define HF 24
#define XSTRIDE 1032   // 1029 padded to 1032 (16B-aligned rows)

typedef int iv4 __attribute__((ext_vector_type(4)));

// ---------------- K1: geometry + m_small + pooling, fused -------------------
// One block per (b,k). b = bid&7 so each XCD's L2 caches one batch's fm slab
// (2.36 MB < 4 MB). Each block: (1) sampled gather -> ms[576] + inv_msum;
// (2a) stream all 262144 mask ints (HBM floor) for area/centroid/bbox;
// (2b) pooled[d=tid] = sum_n ms[n]*fm[b,n,d] from L2, + column sum for fmean.
// Phases 2a/2b run in opposite order for co-resident blocks (parity) so the
// HBM pipe and the L2/VALU pipes overlap chip-wide.
__global__ __launch_bounds__(1024) void k_geom(const int* __restrict__ masks,
                                               const float* __restrict__ fm,
                                               float* __restrict__ xbuf) {
    int bid = blockIdx.x;          // 512 blocks
    int b = bid & 7;               // XCD-locality: XCD x handles batch x
    int k = bid >> 3;
    int bk = b * KK + k;           // canonical row index
    int tid = threadIdx.x;         // 1024
    const int* mb = masks + (size_t)bk * (HH * WW);
    const iv4* mp = (const iv4*)mb;

    __shared__ float ms[NN];
    __shared__ float s_inv;
    __shared__ float rsum[16];

    // ---- phase 1: sampled gather for m_small + msum ----
    float msv = 0.f;
    if (tid < NN) {
        int i = tid / HF, j = tid - i * HF;
        int ri = (i * HH) / HF, ci = (j * WW) / HF;
        msv = (mb[ri * WW + ci] != 0) ? 1.f : 0.f;
        ms[tid] = msv;
    }
    {
        float v = msv;
        for (int off = 32; off > 0; off >>= 1) v += __shfl_down(v, off);
        if ((tid & 63) == 0) rsum[tid >> 6] = v;
    }
    __syncthreads();
    if (tid == 0) {
        float s = 0.f;
        for (int i = 0; i < 16; ++i) s += rsum[i];
        s_inv = 1.0f / fmaxf(s, 1e-6f);
    }
    __syncthreads();   // ms[] complete + s_inv ready

    // geometry state (masks values are exactly 0/1: bool -> int32)
    const int y0 = tid >> 7;             // row offset within 8-row stripe
    const int xb = (tid & 127) << 2;     // loop-invariant column base
    int cnt = 0, w3a = 0, syr = 0, colany = 0;
    int ymn_it = 1 << 20, ymx_it = -1;
    // pool state
    float acc = 0.f, facc = 0.f;

    auto STREAM = [&]() {
        #pragma unroll 8
        for (int it = 0; it < 64; ++it) {
            iv4 m = __builtin_nontemporal_load(&mp[tid + (it << 10)]);
            int sum4 = m.x + m.y + m.z + m.w;
            int mask4 = m.x | (m.y << 1) | (m.z << 2) | (m.w << 3);
            cnt += sum4;
            w3a += m.y + (m.z << 1) + ((m.w << 1) + m.w);
            syr += sum4 * it;
            colany |= mask4;
            if (mask4) { ymn_it = min(ymn_it, it); ymx_it = it; }  // y monotone
        }
    };
    auto POOL = [&]() {
        const float* fp = fm + (size_t)b * NN * DD + tid;
        for (int n = 0; n < NN; n += 4) {
            float4 mq = *(const float4*)&ms[n];   // uniform LDS read
            float f0 = fp[(size_t)(n + 0) * DD];
            float f1 = fp[(size_t)(n + 1) * DD];
            float f2 = fp[(size_t)(n + 2) * DD];
            float f3 = fp[(size_t)(n + 3) * DD];
            facc += f0 + f1 + f2 + f3;
            acc = fmaf(mq.x, f0, acc);
            acc = fmaf(mq.y, f1, acc);
            acc = fmaf(mq.z, f2, acc);
            acc = fmaf(mq.w, f3, acc);
        }
    };

    if (((bid ^ (bid >> 8)) & 1) == 0) { STREAM(); POOL(); }
    else                               { POOL(); STREAM(); }

    // pooled/msum - fmean (thread-local, no barrier needed)
    {
        float* xp = xbuf + (size_t)bk * XSTRIDE;
        xp[tid] = acc * s_inv - facc * (1.0f / 576.0f);
    }

    // ---- geometry finalize ----
    int sx = xb * cnt + w3a;
    int sy = (syr << 3) + y0 * cnt;
    int xmn = colany ? xb + __builtin_ctz((unsigned)colany) : (1 << 30);
    int xmx = colany ? xb + (31 - __builtin_clz((unsigned)colany)) : -1;
    int ymn = (ymx_it >= 0) ? (ymn_it << 3) + y0 : (1 << 30);
    int ymx = (ymx_it >= 0) ? (ymx_it << 3) + y0 : -1;

    for (int off = 32; off > 0; off >>= 1) {
        cnt += __shfl_down(cnt, off);
        sx  += __shfl_down(sx,  off);
        sy  += __shfl_down(sy,  off);
        xmn = min(xmn, __shfl_down(xmn, off));
        xmx = max(xmx, __shfl_down(xmx, off));
        ymn = min(ymn, __shfl_down(ymn, off));
        ymx = max(ymx, __shfl_down(ymx, off));
    }
    __shared__ int r0[16], r1[16], r2[16], r3[16], r4[16], r5[16], r6[16];
    int wv = tid >> 6;
    if ((tid & 63) == 0) {
        r0[wv] = cnt; r1[wv] = sx; r2[wv] = sy;
        r3[wv] = xmn; r4[wv] = xmx; r5[wv] = ymn; r6[wv] = ymx;
    }
    __syncthreads();
    if (tid == 0) {
        for (int i = 1; i < 16; ++i) {
            cnt += r0[i]; sx += r1[i]; sy += r2[i];
            xmn = min(xmn, r3[i]); xmx = max(xmx, r4[i]);
            ymn = min(ymn, r5[i]); ymx = max(ymx, r6[i]);
        }
        float* gp = xbuf + (size_t)bk * XSTRIDE + DD;
        if (cnt >= 1) {
            float area = (float)cnt;
            gp[0] = (float)sx / area * (1.0f / 512.0f);
            gp[1] = (float)sy / area * (1.0f / 512.0f);
            gp[2] = area * (1.0f / 262144.0f);
            gp[3] = (float)(xmx - xmn + 1) * (1.0f / 512.0f);
            gp[4] = (float)(ymx - ymn + 1) * (1.0f / 512.0f);
        } else {
            gp[0] = 0.f; gp[1] = 0.f; gp[2] = 0.f; gp[3] = 0.f; gp[4] = 0.f;
        }
        gp[5] = 0.f; gp[6] = 0.f; gp[7] = 0.f;   // pad cols 1029..1031
    }
}

// ---------------- K2: MLP, 4 rows/block, 512 thr, 8-way j-split -------------
__global__ __launch_bounds__(512) void k_mlp(const float* __restrict__ xbuf,
                                             const float* __restrict__ w1,
                                             const float* __restrict__ b1,
                                             const float* __restrict__ ln_g,
                                             const float* __restrict__ ln_b,
                                             const float* __restrict__ w2,
                                             const float* __restrict__ b2,
                                             float* __restrict__ out) {
    int row0 = blockIdx.x * 4;     // 128 blocks
    int tid = threadIdx.x;         // 512
    int w = tid >> 6, lane = tid & 63;
    int c4 = lane * 4;
    int col = tid & 255, rhalf = tid >> 8;

    __shared__ float xs[4][XSTRIDE];      // 16.5 KB
    __shared__ float hp[8][4][OUTD];      // 32 KB partials [wave][row][col]
    __shared__ float hs[4][OUTD];         // 4 KB

    // float4 staging (xbuf rows are 16B-aligned: 1032*4 % 16 == 0)
    for (int i = tid; i < 4 * (XSTRIDE / 4); i += 512) {
        int r = i / (XSTRIDE / 4), cq = i % (XSTRIDE / 4);
        *(float4*)&xs[r][cq * 4] =
            *(const float4*)&xbuf[(size_t)(row0 + r) * XSTRIDE + cq * 4];
    }
    __syncthreads();

    // ---- phase A: h = x @ w1, j-range per wave (16B-aligned splits) ----
    float acc[4][4] = {};
    int js = w * 128;
    int je = (w == 7) ? 1029 : js + 128;
    int j = js;
    for (; j + 4 <= je; j += 4) {
        float4 xv0 = *(const float4*)&xs[0][j];
        float4 xv1 = *(const float4*)&xs[1][j];
        float4 xv2 = *(const float4*)&xs[2][j];
        float4 xv3 = *(const float4*)&xs[3][j];
#define STEPA(jj, X0, X1, X2, X3)                                              \
        {                                                                      \
            float4 wv = *(const float4*)&w1[(size_t)(j + jj) * OUTD + c4];     \
            acc[0][0] += X0 * wv.x; acc[0][1] += X0 * wv.y;                    \
            acc[0][2] += X0 * wv.z; acc[0][3] += X0 * wv.w;                    \
            acc[1][0] += X1 * wv.x; acc[1][1] += X1 * wv.y;                    \
            acc[1][2] += X1 * wv.z; acc[1][3] += X1 * wv.w;                    \
            acc[2][0] += X2 * wv.x; acc[2][1] += X2 * wv.y;                    \
            acc[2][2] += X2 * wv.z; acc[2][3] += X2 * wv.w;                    \
            acc[3][0] += X3 * wv.x; acc[3][1] += X3 * wv.y;                    \
            acc[3][2] += X3 * wv.z; acc[3][3] += X3 * wv.w;                    \
        }
        STEPA(0, xv0.x, xv1.x, xv2.x, xv3.x)
        STEPA(1, xv0.y, xv1.y, xv2.y, xv3.y)
        STEPA(2, xv0.z, xv1.z, xv2.z, xv3.z)
        STEPA(3, xv0.w, xv1.w, xv2.w, xv3.w)
    }
    for (; j < je; ++j) {   // tail (wave 7: j = 1028)
        float xv[4] = {xs[0][j], xs[1][j], xs[2][j], xs[3][j]};
        #pragma unroll
        for (int ci = 0; ci < 4; ++ci) {
            float wvv = w1[(size_t)j * OUTD + c4 + ci];
            #pragma unroll
            for (int r = 0; r < 4; ++r) acc[r][ci] += xv[r] * wvv;
        }
    }
    #pragma unroll
    for (int r = 0; r < 4; ++r)
        *(float4*)&hp[w][r][c4] = make_float4(acc[r][0], acc[r][1], acc[r][2], acc[r][3]);
    __syncthreads();

    // ---- reduce partials, GELU, LayerNorm (thread = (rhalf, col)) ----
    float h2[2];
    float b1v = b1[col];
    #pragma unroll
    for (int r2 = 0; r2 < 2; ++r2) {
        int r = rhalf * 2 + r2;
        float s = b1v;
        #pragma unroll
        for (int ww = 0; ww < 8; ++ww) s += hp[ww][r][col];
        h2[r2] = 0.5f * s * (1.0f + erff(s * 0.70710678118654752f));
    }
    __shared__ float s1[8][2], s2[8][2];
    #pragma unroll
    for (int r2 = 0; r2 < 2; ++r2) {
        float a = h2[r2], q = h2[r2] * h2[r2];
        for (int off = 32; off > 0; off >>= 1) {
            a += __shfl_down(a, off);
            q += __shfl_down(q, off);
        }
        if (lane == 0) { s1[w][r2] = a; s2[w][r2] = q; }
    }
    __syncthreads();
    __shared__ float mu_[4], rsd_[4];
    if (tid < 4) {
        int rh = tid >> 1, r2 = tid & 1;
        float a = 0.f, q = 0.f;
        #pragma unroll
        for (int i = 0; i < 4; ++i) {
            a += s1[rh * 4 + i][r2];
            q += s2[rh * 4 + i][r2];
        }
        float mu = a * (1.0f / 256.0f);
        float var = q * (1.0f / 256.0f) - mu * mu;
        mu_[tid] = mu;
        rsd_[tid] = rsqrtf(var + 1e-5f);
    }
    __syncthreads();
    float gv = ln_g[col], bv = ln_b[col];
    #pragma unroll
    for (int r2 = 0; r2 < 2; ++r2) {
        int r = rhalf * 2 + r2;
        hs[r][col] = (h2[r2] - mu_[r]) * rsd_[r] * gv + bv;
    }
    __syncthreads();

    // ---- phase B: out = hs @ w2, j-range per wave (32 each) ----
    float a2[4][4] = {};
    int j2 = w * 32;
    for (int g = 0; g < 8; ++g, j2 += 4) {
        float4 h0 = *(const float4*)&hs[0][j2];
        float4 h1 = *(const float4*)&hs[1][j2];
        float4 h2v = *(const float4*)&hs[2][j2];
        float4 h3 = *(const float4*)&hs[3][j2];
#define STEPB(jj, X0, X1, X2, X3)                                              \
        {                                                                      \
            float4 wv = *(const float4*)&w2[(size_t)(j2 + jj) * OUTD + c4];    \
            a2[0][0] += X0 * wv.x; a2[0][1] += X0 * wv.y;                      \
            a2[0][2] += X0 * wv.z; a2[0][3] += X0 * wv.w;                      \
            a2[1][0] += X1 * wv.x; a2[1][1] += X1 * wv.y;                      \
            a2[1][2] += X1 * wv.z; a2[1][3] += X1 * wv.w;                      \
            a2[2][0] += X2 * wv.x; a2[2][1] += X2 * wv.y;                      \
            a2[2][2] += X2 * wv.z; a2[2][3] += X2 * wv.w;                      \
            a2[3][0] += X3 * wv.x; a2[3][1] += X3 * wv.y;                      \
            a2[3][2] += X3 * wv.z; a2[3][3] += X3 * wv.w;                      \
        }
        STEPB(0, h0.x, h1.x, h2v.x, h3.x)
        STEPB(1, h0.y, h1.y, h2v.y, h3.y)
        STEPB(2, h0.z, h1.z, h2v.z, h3.z)
        STEPB(3, h0.w, h1.w, h2v.w, h3.w)
    }
    #pragma unroll
    for (int r = 0; r < 4; ++r)
        *(float4*)&hp[w][r][c4] = make_float4(a2[r][0], a2[r][1], a2[r][2], a2[r][3]);
    __syncthreads();

    float b2v = b2[col];
    #pragma unroll
    for (int r2 = 0; r2 < 2; ++r2) {
        int r = rhalf * 2 + r2;
        float o = b2v;
        #pragma unroll
        for (int ww = 0; ww < 8; ++ww) o += hp[ww][r][col];
        out[(size_t)(row0 + r) * OUTD + col] = o;
    }
}

extern "C" void kernel_launch(void* const* d_in, const int* in_sizes, int n_in,
                              void* d_out, int out_size, void* d_ws, size_t ws_size,
                              hipStream_t stream) {
    const float* fm    = (const float*)d_in[0];
    const int*   masks = (const int*)d_in[1];
    const float* w1    = (const float*)d_in[2];
    const float* b1    = (const float*)d_in[3];
    const float* ln_g  = (const float*)d_in[4];
    const float* ln_b  = (const float*)d_in[5];
    const float* w2    = (const float*)d_in[6];
    const float* b2    = (const float*)d_in[7];
    float* out = (float*)d_out;

    float* xbuf = (float*)d_ws;                  // 512*1032 floats ≈ 2.11 MB

    k_geom<<<512, 1024, 0, stream>>>(masks, fm, xbuf);
    k_mlp <<<128, 512, 0, stream>>>(xbuf, w1, b1, ln_g, ln_b, w2, b2, out);
}